// Round 1
// baseline (1181.651 us; speedup 1.0000x reference)
//
#include <hip/hip_runtime.h>
#include <hip/hip_bf16.h>

// Problem constants
#define NN 4096
#define PP 128
#define QQ 128
#define HD 256
#define KH 8
#define DD 64

// ---------------------------------------------------------------------------
// K1: bilinear  x[n,h] = sum_{p,q} xp[n,p]*xn[n,q]*W[h,p,q] + b[h]
// GEMM C[4096,256] = Z[4096,16384] @ W[256,16384]^T with Z formed on the fly.
// Tile: 64n x 64h per block (256 thr), 4x4 accum per thread.
// LDS: xn_t[128q][68] + w_t[64q][68] (per p, q-half) + xp_c[32p][68] = ~60.9KB
// ---------------------------------------------------------------------------
__global__ __launch_bounds__(256) void k1_bilinear(
    const float* __restrict__ xp, const float* __restrict__ xn,
    const float* __restrict__ W, const float* __restrict__ bb,
    float* __restrict__ xout) {
  __shared__ float xn_t[128][68];
  __shared__ float w_t[64][68];
  __shared__ float xp_c[32][68];
  const int t  = threadIdx.x;
  const int n0 = blockIdx.x * 64, h0 = blockIdx.y * 64;
  const int nb = 4 * (t & 15), hb = 4 * (t >> 4);
  const int ql_s = t & 63, hl_s = t >> 6;  // W staging map

  // stage xn transposed: xn_t[q][n_local]
  for (int idx = t; idx < 64 * 128; idx += 256) {
    int nl = idx >> 7, q = idx & 127;
    xn_t[q][nl] = xn[(n0 + nl) * PP + q];
  }

  float acc[4][4] = {{0.f, 0.f, 0.f, 0.f}, {0.f, 0.f, 0.f, 0.f},
                     {0.f, 0.f, 0.f, 0.f}, {0.f, 0.f, 0.f, 0.f}};
  float wr[16];
  // prefetch W stage 0 (p=0, qh=0): element (ql_s, hl_s+4s)
  {
    const float* wp = W + (h0 + hl_s) * (PP * QQ) + ql_s;
#pragma unroll
    for (int s = 0; s < 16; ++s) wr[s] = wp[s * 4 * (PP * QQ)];
  }
  __syncthreads();  // xn_t ready

  int stage = 0;
  for (int pc = 0; pc < PP; pc += 32) {
    __syncthreads();  // xp_c free
    for (int idx = t; idx < 32 * 64; idx += 256) {
      int pl = idx & 31, nl = idx >> 5;
      xp_c[pl][nl] = xp[(n0 + nl) * PP + pc + pl];
    }
    __syncthreads();  // xp_c ready
    for (int pl = 0; pl < 32; ++pl) {
      const float4 xpv = *(const float4*)&xp_c[pl][nb];
      for (int qh = 0; qh < QQ; qh += 64) {
        __syncthreads();  // w_t free
#pragma unroll
        for (int s = 0; s < 16; ++s) w_t[ql_s][hl_s + 4 * s] = wr[s];
        ++stage;
        if (stage < 256) {
          const int pn = stage >> 1, qn = (stage & 1) * 64;
          const float* wp = W + (h0 + hl_s) * (PP * QQ) + pn * QQ + qn + ql_s;
#pragma unroll
          for (int s = 0; s < 16; ++s) wr[s] = wp[s * 4 * (PP * QQ)];
        }
        __syncthreads();  // w_t ready
#pragma unroll 8
        for (int q = 0; q < 64; ++q) {
          const float4 xnv = *(const float4*)&xn_t[qh + q][nb];
          const float4 wv  = *(const float4*)&w_t[q][hb];
          const float z0 = xpv.x * xnv.x, z1 = xpv.y * xnv.y;
          const float z2 = xpv.z * xnv.z, z3 = xpv.w * xnv.w;
          acc[0][0] += z0 * wv.x; acc[0][1] += z0 * wv.y;
          acc[0][2] += z0 * wv.z; acc[0][3] += z0 * wv.w;
          acc[1][0] += z1 * wv.x; acc[1][1] += z1 * wv.y;
          acc[1][2] += z1 * wv.z; acc[1][3] += z1 * wv.w;
          acc[2][0] += z2 * wv.x; acc[2][1] += z2 * wv.y;
          acc[2][2] += z2 * wv.z; acc[2][3] += z2 * wv.w;
          acc[3][0] += z3 * wv.x; acc[3][1] += z3 * wv.y;
          acc[3][2] += z3 * wv.z; acc[3][3] += z3 * wv.w;
        }
      }
    }
  }
  const float4 bv = *(const float4*)&bb[h0 + hb];
#pragma unroll
  for (int i = 0; i < 4; ++i) {
    float4 o;
    o.x = acc[i][0] + bv.x; o.y = acc[i][1] + bv.y;
    o.z = acc[i][2] + bv.z; o.w = acc[i][3] + bv.w;
    *(float4*)&xout[(n0 + nb + i) * HD + h0 + hb] = o;
  }
}

// ---------------------------------------------------------------------------
// K2: xt[k][n][d] = sum_h x[n][h] * Wt[k][d][h]
// Tile 64n x 64d (full D) per block, k-chunked h by 64.
// ---------------------------------------------------------------------------
__global__ __launch_bounds__(256) void k2_xt(
    const float* __restrict__ x, const float* __restrict__ Wt,
    float* __restrict__ xt) {
  __shared__ float x_t[64][68];
  __shared__ float wt_t[64][68];
  const int t = threadIdx.x;
  const int n0 = blockIdx.x * 64;
  const int k  = blockIdx.y;
  const int nb = 4 * (t & 15), db = 4 * (t >> 4);
  float acc[4][4] = {{0.f, 0.f, 0.f, 0.f}, {0.f, 0.f, 0.f, 0.f},
                     {0.f, 0.f, 0.f, 0.f}, {0.f, 0.f, 0.f, 0.f}};
  for (int h0 = 0; h0 < HD; h0 += 64) {
    __syncthreads();
    for (int idx = t; idx < 4096; idx += 256) {
      int hl = idx & 63, r = idx >> 6;
      x_t[hl][r]  = x[(n0 + r) * HD + h0 + hl];
      wt_t[hl][r] = Wt[k * (DD * HD) + r * HD + h0 + hl];
    }
    __syncthreads();
#pragma unroll 8
    for (int h = 0; h < 64; ++h) {
      const float4 xv = *(const float4*)&x_t[h][nb];
      const float4 wv = *(const float4*)&wt_t[h][db];
      acc[0][0] += xv.x * wv.x; acc[0][1] += xv.x * wv.y;
      acc[0][2] += xv.x * wv.z; acc[0][3] += xv.x * wv.w;
      acc[1][0] += xv.y * wv.x; acc[1][1] += xv.y * wv.y;
      acc[1][2] += xv.y * wv.z; acc[1][3] += xv.y * wv.w;
      acc[2][0] += xv.z * wv.x; acc[2][1] += xv.z * wv.y;
      acc[2][2] += xv.z * wv.z; acc[2][3] += xv.z * wv.w;
      acc[3][0] += xv.w * wv.x; acc[3][1] += xv.w * wv.y;
      acc[3][2] += xv.w * wv.z; acc[3][3] += xv.w * wv.w;
    }
  }
#pragma unroll
  for (int i = 0; i < 4; ++i) {
    float4 o;
    o.x = acc[i][0]; o.y = acc[i][1]; o.z = acc[i][2]; o.w = acc[i][3];
    *(float4*)&xt[(k * NN + n0 + nb + i) * DD + db] = o;
  }
}

// ---------------------------------------------------------------------------
// K3: s_src[k][n] = xt[k][n][:]·a_vec[k][:64], s_dst with a_vec[k][64:]
// ---------------------------------------------------------------------------
__global__ __launch_bounds__(256) void k3_scores(
    const float* __restrict__ xt, const float* __restrict__ av,
    float* __restrict__ ssrc, float* __restrict__ sdst) {
  const int tid = blockIdx.x * 256 + threadIdx.x;  // == k*4096+n
  const int k = tid >> 12;
  const float* xr = xt + (long)tid * DD;
  const float* a = av + k * (2 * DD);
  float s1 = 0.f, s2 = 0.f;
#pragma unroll
  for (int d = 0; d < DD; d += 4) {
    const float4 xv = *(const float4*)&xr[d];
    const float4 a1 = *(const float4*)&a[d];
    const float4 a2 = *(const float4*)&a[DD + d];
    s1 += xv.x * a1.x + xv.y * a1.y + xv.z * a1.z + xv.w * a1.w;
    s2 += xv.x * a2.x + xv.y * a2.y + xv.z * a2.z + xv.w * a2.w;
  }
  ssrc[tid] = s1;
  sdst[tid] = s2;
}

// ---------------------------------------------------------------------------
// K5: attention + output.
// scores bounded (|u|,|v| <~ 8) so exp() without max-subtraction is safe in fp32.
// Block = (k, 64-n tile); loop m in chunks of 64: stage xt chunk + w tile in
// LDS, accumulate 4n x 4d per thread; denominator via per-thread partials.
// out[n, k*64+d] = tanh(acc/denom)
// ---------------------------------------------------------------------------
__global__ __launch_bounds__(256) void k5_attn(
    const float* __restrict__ xt, const float* __restrict__ ssrc,
    const float* __restrict__ sdst, float* __restrict__ out) {
  __shared__ float xts[64][64];
  __shared__ float wsm[64][68];
  __shared__ float us[64];
  __shared__ float dpart[4][64];
  __shared__ float dfull[64];
  const int t  = threadIdx.x;
  const int n0 = blockIdx.x * 64;
  const int k  = blockIdx.y;
  const int nb = 4 * (t & 15), db = 4 * (t >> 4);
  const int nl = t & 63, mq = t >> 6;
  if (t < 64) us[t] = ssrc[k * NN + n0 + t];
  __syncthreads();
  const float u = us[nl];
  const float* sd = sdst + k * NN;
  float acc[4][4] = {{0.f, 0.f, 0.f, 0.f}, {0.f, 0.f, 0.f, 0.f},
                     {0.f, 0.f, 0.f, 0.f}, {0.f, 0.f, 0.f, 0.f}};
  float dsum = 0.f;
  for (int m0 = 0; m0 < NN; m0 += 64) {
    __syncthreads();  // previous readers done
    for (int idx = t; idx < 4096; idx += 256) {
      int d = idx & 63, ml = idx >> 6;
      xts[ml][d] = xt[(k * NN + m0 + ml) * DD + d];
    }
#pragma unroll
    for (int r = 0; r < 16; ++r) {
      const int ml = mq + 4 * r;
      float sc = u + sd[m0 + ml];
      sc = sc >= 0.f ? sc : 0.2f * sc;
      const float w = __expf(sc);
      dsum += w;
      wsm[ml][nl] = w;
    }
    __syncthreads();
#pragma unroll 4
    for (int m = 0; m < 64; ++m) {
      const float4 wv = *(const float4*)&wsm[m][nb];
      const float4 xv = *(const float4*)&xts[m][db];
      acc[0][0] += wv.x * xv.x; acc[0][1] += wv.x * xv.y;
      acc[0][2] += wv.x * xv.z; acc[0][3] += wv.x * xv.w;
      acc[1][0] += wv.y * xv.x; acc[1][1] += wv.y * xv.y;
      acc[1][2] += wv.y * xv.z; acc[1][3] += wv.y * xv.w;
      acc[2][0] += wv.z * xv.x; acc[2][1] += wv.z * xv.y;
      acc[2][2] += wv.z * xv.z; acc[2][3] += wv.z * xv.w;
      acc[3][0] += wv.w * xv.x; acc[3][1] += wv.w * xv.y;
      acc[3][2] += wv.w * xv.z; acc[3][3] += wv.w * xv.w;
    }
  }
  dpart[mq][nl] = dsum;
  __syncthreads();
  if (t < 64) dfull[t] = dpart[0][t] + dpart[1][t] + dpart[2][t] + dpart[3][t];
  __syncthreads();
#pragma unroll
  for (int i = 0; i < 4; ++i) {
    const float inv = 1.f / dfull[nb + i];
    float4 o;
    o.x = tanhf(acc[i][0] * inv);
    o.y = tanhf(acc[i][1] * inv);
    o.z = tanhf(acc[i][2] * inv);
    o.w = tanhf(acc[i][3] * inv);
    *(float4*)&out[(long)(n0 + nb + i) * (KH * DD) + k * DD + db] = o;
  }
}

extern "C" void kernel_launch(void* const* d_in, const int* in_sizes, int n_in,
                              void* d_out, int out_size, void* d_ws, size_t ws_size,
                              hipStream_t stream) {
  const float* xp = (const float*)d_in[0];  // (4096,128)
  const float* xn = (const float*)d_in[1];  // (4096,128)
  const float* W  = (const float*)d_in[2];  // (256,128,128)
  const float* bb = (const float*)d_in[3];  // (256,)
  const float* Wt = (const float*)d_in[4];  // (8,64,256)
  const float* av = (const float*)d_in[5];  // (8,128)
  float* out = (float*)d_out;               // (4096, 512)

  char* ws = (char*)d_ws;
  float* x    = (float*)(ws);                                   // 4096*256
  float* xt   = (float*)(ws + (size_t)NN * HD * 4);             // 8*4096*64
  float* ssrc = (float*)(ws + (size_t)NN * HD * 4 + (size_t)KH * NN * DD * 4);
  float* sdst = ssrc + KH * NN;

  k1_bilinear<<<dim3(NN / 64, HD / 64), 256, 0, stream>>>(xp, xn, W, bb, x);
  k2_xt<<<dim3(NN / 64, KH), 256, 0, stream>>>(x, Wt, xt);
  k3_scores<<<(KH * NN) / 256, 256, 0, stream>>>(xt, av, ssrc, sdst);
  k5_attn<<<dim3(NN / 64, KH), 256, 0, stream>>>(xt, ssrc, sdst, out);
}

// Round 2
// 608.222 us; speedup vs baseline: 1.9428x; 1.9428x over previous
//
#include <hip/hip_runtime.h>
#include <hip/hip_bf16.h>

typedef unsigned short ushort;
typedef unsigned int uint;

#define NN 4096
#define PP 128
#define QQ 128
#define HD 256
#define KH 8
#define DD 64
#define KK 16384  // P*Q

typedef short bf16x8 __attribute__((ext_vector_type(8)));
typedef float f32x4 __attribute__((ext_vector_type(4)));

__device__ inline void async_lds16(const void* g, void* l) {
  __builtin_amdgcn_global_load_lds(
      (const __attribute__((address_space(1))) unsigned int*)g,
      (__attribute__((address_space(3))) unsigned int*)l, 16, 0, 0);
}

__device__ inline uint bf16_rne_hibits(float z) {  // returns (bf16 bits)<<16
  uint u = __float_as_uint(z);
  return (u + 0x7FFFu + ((u >> 16) & 1u)) & 0xFFFF0000u;
}

// ---------------------------------------------------------------------------
// K0: split W fp32 -> bf16 hi + bf16 lo (residual)
// ---------------------------------------------------------------------------
__global__ __launch_bounds__(256) void k0_split(
    const float* __restrict__ W, ushort* __restrict__ hi, ushort* __restrict__ lo) {
  const int i = (blockIdx.x * 256 + threadIdx.x) * 4;
  const float4 w = *(const float4*)&W[i];
  ushort h4[4], l4[4];
  const float wf[4] = {w.x, w.y, w.z, w.w};
#pragma unroll
  for (int j = 0; j < 4; ++j) {
    uint hb = bf16_rne_hibits(wf[j]);
    h4[j] = hb >> 16;
    float r = wf[j] - __uint_as_float(hb);
    l4[j] = bf16_rne_hibits(r) >> 16;
  }
  *(ushort4*)&hi[i] = *(ushort4*)h4;
  *(ushort4*)&lo[i] = *(ushort4*)l4;
}

__global__ __launch_bounds__(256) void k_zero(float* __restrict__ p) {
  p[blockIdx.x * 256 + threadIdx.x] = 0.f;
}

// ---------------------------------------------------------------------------
// K1: bilinear via split-bf16 MFMA.  C[4096,256] = Z @ Wsplit^T, Z on the fly.
// Block 128n x 128h (4 waves, 64x64 each), BK=32, K-split 8 -> atomicAdd.
// ---------------------------------------------------------------------------
__global__ __launch_bounds__(256, 2) void k1_bilinear(
    const float* __restrict__ xp, const float* __restrict__ xn,
    const ushort* __restrict__ Whi, const ushort* __restrict__ Wlo,
    float* __restrict__ xout) {
  __shared__ ushort whi[128 * 32];   // [h][k] unpadded, XOR-swizzled segs
  __shared__ ushort wlo[128 * 32];
  __shared__ ushort zhi[128 * 40];   // [n][k] padded 32->40
  __shared__ ushort zlo[128 * 40];
  __shared__ float xpt[16][128];     // [p][n]

  const int t = threadIdx.x;
  const int n0 = blockIdx.x * 128;
  const int h0 = blockIdx.y * 128;
  const int kb = blockIdx.z * (KK / 8);   // 2048-wide K chunk
  const int pb = kb >> 7;                 // 16 p values per block

  // stage xp tile once: xpt[p][n]
  for (int idx = t; idx < 2048; idx += 256) {
    const int p = idx & 15, n = idx >> 4;
    xpt[p][n] = xp[(size_t)(n0 + n) * PP + pb + p];
  }

  // wave / lane decomposition
  const int l = t & 63, w = t >> 6;
  const int wr = (w >> 1) * 64, wc = (w & 1) * 64;

  // fragment LDS offsets (loop-invariant)
  int aoff[4], boff[4];
#pragma unroll
  for (int i = 0; i < 4; ++i)
    aoff[i] = (wr + i * 16 + (l & 15)) * 40 + (l >> 4) * 8;
#pragma unroll
  for (int j = 0; j < 4; ++j) {
    const int hr = wc + j * 16 + (l & 15);
    boff[j] = hr * 32 + (((l >> 4) ^ ((hr ^ (hr >> 2)) & 3)) * 8);
  }

  // W staging maps (global_load_lds: lds dst must be base + lane*16)
  const int sh1 = t >> 2, seg = t & 3;
  const int g1 = seg ^ ((sh1 ^ (sh1 >> 2)) & 3);
  const int sh2 = sh1 + 64;
  const int g2 = seg ^ ((sh2 ^ (sh2 >> 2)) & 3);

  // z-formation map
  const int zn = t >> 1, zko = (t & 1) * 16;

  f32x4 acc[4][4];
#pragma unroll
  for (int i = 0; i < 4; ++i)
#pragma unroll
    for (int j = 0; j < 4; ++j) acc[i][j] = (f32x4)0.f;

  for (int c = 0; c < 64; ++c) {
    const int kc = kb + c * 32;
    const int pl = c >> 2;                 // local p index
    const int q0 = (c & 3) * 32;           // q base within row

    __syncthreads();  // previous step's fragment reads done

    // async stage W hi/lo tiles (128h x 32k bf16 each)
    async_lds16(Whi + (size_t)(h0 + sh1) * KK + kc + g1 * 8, whi + sh1 * 32 + seg * 8);
    async_lds16(Whi + (size_t)(h0 + sh2) * KK + kc + g2 * 8, whi + sh2 * 32 + seg * 8);
    async_lds16(Wlo + (size_t)(h0 + sh1) * KK + kc + g1 * 8, wlo + sh1 * 32 + seg * 8);
    async_lds16(Wlo + (size_t)(h0 + sh2) * KK + kc + g2 * 8, wlo + sh2 * 32 + seg * 8);

    // form Z tile: 16 elements per thread (row zn, k = zko..zko+16)
    {
      const float xpv = xpt[pl][zn];
      const float* xr = xn + (size_t)(n0 + zn) * QQ + q0 + zko;
      float4 v0 = ((const float4*)xr)[0];
      float4 v1 = ((const float4*)xr)[1];
      float4 v2 = ((const float4*)xr)[2];
      float4 v3 = ((const float4*)xr)[3];
      float zz[16] = {v0.x, v0.y, v0.z, v0.w, v1.x, v1.y, v1.z, v1.w,
                      v2.x, v2.y, v2.z, v2.w, v3.x, v3.y, v3.z, v3.w};
      union { ushort s[16]; uint4 q[2]; } uh, ul;
#pragma unroll
      for (int j = 0; j < 16; ++j) {
        const float z = xpv * zz[j];
        const uint hb = bf16_rne_hibits(z);
        uh.s[j] = hb >> 16;
        const float r = z - __uint_as_float(hb);
        ul.s[j] = bf16_rne_hibits(r) >> 16;
      }
      const int zo = zn * 40 + zko;
      *(uint4*)&zhi[zo] = uh.q[0];
      *(uint4*)&zhi[zo + 8] = uh.q[1];
      *(uint4*)&zlo[zo] = ul.q[0];
      *(uint4*)&zlo[zo + 8] = ul.q[1];
    }

    __syncthreads();  // W (vmcnt drained by compiler) + Z visible

    bf16x8 Ah[4], Al[4], Bh[4], Bl[4];
#pragma unroll
    for (int i = 0; i < 4; ++i) {
      Ah[i] = *(const bf16x8*)&zhi[aoff[i]];
      Al[i] = *(const bf16x8*)&zlo[aoff[i]];
    }
#pragma unroll
    for (int j = 0; j < 4; ++j) {
      Bh[j] = *(const bf16x8*)&whi[boff[j]];
      Bl[j] = *(const bf16x8*)&wlo[boff[j]];
    }
#pragma unroll
    for (int i = 0; i < 4; ++i)
#pragma unroll
      for (int j = 0; j < 4; ++j) {
        acc[i][j] = __builtin_amdgcn_mfma_f32_16x16x32_bf16(Ah[i], Bh[j], acc[i][j], 0, 0, 0);
        acc[i][j] = __builtin_amdgcn_mfma_f32_16x16x32_bf16(Ah[i], Bl[j], acc[i][j], 0, 0, 0);
        acc[i][j] = __builtin_amdgcn_mfma_f32_16x16x32_bf16(Al[i], Bh[j], acc[i][j], 0, 0, 0);
      }
  }

  // epilogue: atomic accumulate (K-split partials collide here)
#pragma unroll
  for (int i = 0; i < 4; ++i)
#pragma unroll
    for (int j = 0; j < 4; ++j) {
      const int row = n0 + wr + i * 16 + (l >> 4) * 4;
      const int col = h0 + wc + j * 16 + (l & 15);
#pragma unroll
      for (int r = 0; r < 4; ++r)
        atomicAdd(&xout[(size_t)(row + r) * HD + col], acc[i][j][r]);
    }
}

// ---------------------------------------------------------------------------
// K2: xt[k][n][d] = sum_h (x[n][h]+b[h]) * Wt[k][d][h]
// ---------------------------------------------------------------------------
__global__ __launch_bounds__(256) void k2_xt(
    const float* __restrict__ x, const float* __restrict__ bb,
    const float* __restrict__ Wt, float* __restrict__ xt) {
  __shared__ float x_t[64][68];
  __shared__ float wt_t[64][68];
  const int t = threadIdx.x;
  const int n0 = blockIdx.x * 64;
  const int k = blockIdx.y;
  const int nb = 4 * (t & 15), db = 4 * (t >> 4);
  float acc[4][4] = {{0.f, 0.f, 0.f, 0.f}, {0.f, 0.f, 0.f, 0.f},
                     {0.f, 0.f, 0.f, 0.f}, {0.f, 0.f, 0.f, 0.f}};
  for (int h0 = 0; h0 < HD; h0 += 64) {
    __syncthreads();
    for (int idx = t; idx < 4096; idx += 256) {
      int hl = idx & 63, r = idx >> 6;
      x_t[hl][r] = x[(n0 + r) * HD + h0 + hl] + bb[h0 + hl];
      wt_t[hl][r] = Wt[k * (DD * HD) + r * HD + h0 + hl];
    }
    __syncthreads();
#pragma unroll 8
    for (int h = 0; h < 64; ++h) {
      const float4 xv = *(const float4*)&x_t[h][nb];
      const float4 wv = *(const float4*)&wt_t[h][db];
      acc[0][0] += xv.x * wv.x; acc[0][1] += xv.x * wv.y;
      acc[0][2] += xv.x * wv.z; acc[0][3] += xv.x * wv.w;
      acc[1][0] += xv.y * wv.x; acc[1][1] += xv.y * wv.y;
      acc[1][2] += xv.y * wv.z; acc[1][3] += xv.y * wv.w;
      acc[2][0] += xv.z * wv.x; acc[2][1] += xv.z * wv.y;
      acc[2][2] += xv.z * wv.z; acc[2][3] += xv.z * wv.w;
      acc[3][0] += xv.w * wv.x; acc[3][1] += xv.w * wv.y;
      acc[3][2] += xv.w * wv.z; acc[3][3] += xv.w * wv.w;
    }
  }
#pragma unroll
  for (int i = 0; i < 4; ++i) {
    float4 o;
    o.x = acc[i][0]; o.y = acc[i][1]; o.z = acc[i][2]; o.w = acc[i][3];
    *(float4*)&xt[(k * NN + n0 + nb + i) * DD + db] = o;
  }
}

// ---------------------------------------------------------------------------
// K3: s_src / s_dst dots
// ---------------------------------------------------------------------------
__global__ __launch_bounds__(256) void k3_scores(
    const float* __restrict__ xt, const float* __restrict__ av,
    float* __restrict__ ssrc, float* __restrict__ sdst) {
  const int tid = blockIdx.x * 256 + threadIdx.x;
  const int k = tid >> 12;
  const float* xr = xt + (long)tid * DD;
  const float* a = av + k * (2 * DD);
  float s1 = 0.f, s2 = 0.f;
#pragma unroll
  for (int d = 0; d < DD; d += 4) {
    const float4 xv = *(const float4*)&xr[d];
    const float4 a1 = *(const float4*)&a[d];
    const float4 a2 = *(const float4*)&a[DD + d];
    s1 += xv.x * a1.x + xv.y * a1.y + xv.z * a1.z + xv.w * a1.w;
    s2 += xv.x * a2.x + xv.y * a2.y + xv.z * a2.z + xv.w * a2.w;
  }
  ssrc[tid] = s1;
  sdst[tid] = s2;
}

// ---------------------------------------------------------------------------
// K5: attention + output (fp32 VALU; next round's MFMA target)
// ---------------------------------------------------------------------------
__global__ __launch_bounds__(256) void k5_attn(
    const float* __restrict__ xt, const float* __restrict__ ssrc,
    const float* __restrict__ sdst, float* __restrict__ out) {
  __shared__ float xts[64][64];
  __shared__ float wsm[64][68];
  __shared__ float us[64];
  __shared__ float dpart[4][64];
  __shared__ float dfull[64];
  const int t = threadIdx.x;
  const int n0 = blockIdx.x * 64;
  const int k = blockIdx.y;
  const int nb = 4 * (t & 15), db = 4 * (t >> 4);
  const int nl = t & 63, mq = t >> 6;
  if (t < 64) us[t] = ssrc[k * NN + n0 + t];
  __syncthreads();
  const float u = us[nl];
  const float* sd = sdst + k * NN;
  float acc[4][4] = {{0.f, 0.f, 0.f, 0.f}, {0.f, 0.f, 0.f, 0.f},
                     {0.f, 0.f, 0.f, 0.f}, {0.f, 0.f, 0.f, 0.f}};
  float dsum = 0.f;
  for (int m0 = 0; m0 < NN; m0 += 64) {
    __syncthreads();
    for (int idx = t; idx < 4096; idx += 256) {
      int d = idx & 63, ml = idx >> 6;
      xts[ml][d] = xt[(k * NN + m0 + ml) * DD + d];
    }
#pragma unroll
    for (int r = 0; r < 16; ++r) {
      const int ml = mq + 4 * r;
      float sc = u + sd[m0 + ml];
      sc = sc >= 0.f ? sc : 0.2f * sc;
      const float wgt = __expf(sc);
      dsum += wgt;
      wsm[ml][nl] = wgt;
    }
    __syncthreads();
#pragma unroll 4
    for (int m = 0; m < 64; ++m) {
      const float4 wv = *(const float4*)&wsm[m][nb];
      const float4 xv = *(const float4*)&xts[m][db];
      acc[0][0] += wv.x * xv.x; acc[0][1] += wv.x * xv.y;
      acc[0][2] += wv.x * xv.z; acc[0][3] += wv.x * xv.w;
      acc[1][0] += wv.y * xv.x; acc[1][1] += wv.y * xv.y;
      acc[1][2] += wv.y * xv.z; acc[1][3] += wv.y * xv.w;
      acc[2][0] += wv.z * xv.x; acc[2][1] += wv.z * xv.y;
      acc[2][2] += wv.z * xv.z; acc[2][3] += wv.z * xv.w;
      acc[3][0] += wv.w * xv.x; acc[3][1] += wv.w * xv.y;
      acc[3][2] += wv.w * xv.z; acc[3][3] += wv.w * xv.w;
    }
  }
  dpart[mq][nl] = dsum;
  __syncthreads();
  if (t < 64) dfull[t] = dpart[0][t] + dpart[1][t] + dpart[2][t] + dpart[3][t];
  __syncthreads();
#pragma unroll
  for (int i = 0; i < 4; ++i) {
    const float inv = 1.f / dfull[nb + i];
    float4 o;
    o.x = tanhf(acc[i][0] * inv);
    o.y = tanhf(acc[i][1] * inv);
    o.z = tanhf(acc[i][2] * inv);
    o.w = tanhf(acc[i][3] * inv);
    *(float4*)&out[(long)(n0 + nb + i) * (KH * DD) + k * DD + db] = o;
  }
}

extern "C" void kernel_launch(void* const* d_in, const int* in_sizes, int n_in,
                              void* d_out, int out_size, void* d_ws, size_t ws_size,
                              hipStream_t stream) {
  const float* xp = (const float*)d_in[0];
  const float* xn = (const float*)d_in[1];
  const float* W = (const float*)d_in[2];
  const float* bb = (const float*)d_in[3];
  const float* Wt = (const float*)d_in[4];
  const float* av = (const float*)d_in[5];
  float* out = (float*)d_out;

  char* ws = (char*)d_ws;
  ushort* Whi = (ushort*)(ws);                       // 8 MB
  ushort* Wlo = (ushort*)(ws + 8388608);             // 8 MB
  float* x    = (float*)(ws + 16777216);             // 4 MB
  float* xt   = (float*)(ws + 20971520);             // 8 MB
  float* ssrc = (float*)(ws + 29360128);             // 128 KB
  float* sdst = ssrc + KH * NN;                      // 128 KB

  k0_split<<<(HD * PP * QQ) / 1024, 256, 0, stream>>>(W, Whi, Wlo);
  k_zero<<<(NN * HD) / 256, 256, 0, stream>>>(x);
  k1_bilinear<<<dim3(NN / 128, HD / 128, 8), 256, 0, stream>>>(xp, xn, Whi, Wlo, x);
  k2_xt<<<dim3(NN / 64, KH), 256, 0, stream>>>(x, bb, Wt, xt);
  k3_scores<<<(KH * NN) / 256, 256, 0, stream>>>(xt, av, ssrc, sdst);
  k5_attn<<<dim3(NN / 64, KH), 256, 0, stream>>>(xt, ssrc, sdst, out);
}

// Round 3
// 371.745 us; speedup vs baseline: 3.1787x; 1.6361x over previous
//
#include <hip/hip_runtime.h>
#include <hip/hip_bf16.h>

typedef unsigned short ushort;
typedef unsigned int uint;

#define NN 4096
#define PP 128
#define QQ 128
#define HD 256
#define KH 8
#define DD 64
#define KK 16384  // P*Q

typedef short bf16x8 __attribute__((ext_vector_type(8)));
typedef float f32x4 __attribute__((ext_vector_type(4)));

__device__ inline void async_lds16(const void* g, void* l) {
  __builtin_amdgcn_global_load_lds(
      (const __attribute__((address_space(1))) unsigned int*)g,
      (__attribute__((address_space(3))) unsigned int*)l, 16, 0, 0);
}

__device__ inline uint bf16_rne_hibits(float z) {  // returns (bf16 bits)<<16
  uint u = __float_as_uint(z);
  return (u + 0x7FFFu + ((u >> 16) & 1u)) & 0xFFFF0000u;
}

// ---------------------------------------------------------------------------
// K0: split W fp32 -> bf16 hi + bf16 lo (residual)
// ---------------------------------------------------------------------------
__global__ __launch_bounds__(256) void k0_split(
    const float* __restrict__ W, ushort* __restrict__ hi, ushort* __restrict__ lo) {
  const int i = (blockIdx.x * 256 + threadIdx.x) * 4;
  const float4 w = *(const float4*)&W[i];
  ushort h4[4], l4[4];
  const float wf[4] = {w.x, w.y, w.z, w.w};
#pragma unroll
  for (int j = 0; j < 4; ++j) {
    uint hb = bf16_rne_hibits(wf[j]);
    h4[j] = hb >> 16;
    float r = wf[j] - __uint_as_float(hb);
    l4[j] = bf16_rne_hibits(r) >> 16;
  }
  *(ushort4*)&hi[i] = *(ushort4*)h4;
  *(ushort4*)&lo[i] = *(ushort4*)l4;
}

__global__ __launch_bounds__(256) void k_zero(float* __restrict__ p) {
  p[blockIdx.x * 256 + threadIdx.x] = 0.f;
}

// ---------------------------------------------------------------------------
// K1: bilinear via split-bf16 MFMA.  C[4096,256] = Z @ Wsplit^T, Z on the fly.
// ---------------------------------------------------------------------------
__global__ __launch_bounds__(256, 2) void k1_bilinear(
    const float* __restrict__ xp, const float* __restrict__ xn,
    const ushort* __restrict__ Whi, const ushort* __restrict__ Wlo,
    float* __restrict__ xout) {
  __shared__ ushort whi[128 * 32];
  __shared__ ushort wlo[128 * 32];
  __shared__ ushort zhi[128 * 40];
  __shared__ ushort zlo[128 * 40];
  __shared__ float xpt[16][128];

  const int t = threadIdx.x;
  const int n0 = blockIdx.x * 128;
  const int h0 = blockIdx.y * 128;
  const int kb = blockIdx.z * (KK / 8);
  const int pb = kb >> 7;

  for (int idx = t; idx < 2048; idx += 256) {
    const int p = idx & 15, n = idx >> 4;
    xpt[p][n] = xp[(size_t)(n0 + n) * PP + pb + p];
  }

  const int l = t & 63, w = t >> 6;
  const int wr = (w >> 1) * 64, wc = (w & 1) * 64;

  int aoff[4], boff[4];
#pragma unroll
  for (int i = 0; i < 4; ++i)
    aoff[i] = (wr + i * 16 + (l & 15)) * 40 + (l >> 4) * 8;
#pragma unroll
  for (int j = 0; j < 4; ++j) {
    const int hr = wc + j * 16 + (l & 15);
    boff[j] = hr * 32 + (((l >> 4) ^ ((hr ^ (hr >> 2)) & 3)) * 8);
  }

  const int sh1 = t >> 2, seg = t & 3;
  const int g1 = seg ^ ((sh1 ^ (sh1 >> 2)) & 3);
  const int sh2 = sh1 + 64;
  const int g2 = seg ^ ((sh2 ^ (sh2 >> 2)) & 3);

  const int zn = t >> 1, zko = (t & 1) * 16;

  f32x4 acc[4][4];
#pragma unroll
  for (int i = 0; i < 4; ++i)
#pragma unroll
    for (int j = 0; j < 4; ++j) acc[i][j] = (f32x4)0.f;

  for (int c = 0; c < 64; ++c) {
    const int kc = kb + c * 32;
    const int pl = c >> 2;
    const int q0 = (c & 3) * 32;

    __syncthreads();

    async_lds16(Whi + (size_t)(h0 + sh1) * KK + kc + g1 * 8, whi + sh1 * 32 + seg * 8);
    async_lds16(Whi + (size_t)(h0 + sh2) * KK + kc + g2 * 8, whi + sh2 * 32 + seg * 8);
    async_lds16(Wlo + (size_t)(h0 + sh1) * KK + kc + g1 * 8, wlo + sh1 * 32 + seg * 8);
    async_lds16(Wlo + (size_t)(h0 + sh2) * KK + kc + g2 * 8, wlo + sh2 * 32 + seg * 8);

    {
      const float xpv = xpt[pl][zn];
      const float* xr = xn + (size_t)(n0 + zn) * QQ + q0 + zko;
      float4 v0 = ((const float4*)xr)[0];
      float4 v1 = ((const float4*)xr)[1];
      float4 v2 = ((const float4*)xr)[2];
      float4 v3 = ((const float4*)xr)[3];
      float zz[16] = {v0.x, v0.y, v0.z, v0.w, v1.x, v1.y, v1.z, v1.w,
                      v2.x, v2.y, v2.z, v2.w, v3.x, v3.y, v3.z, v3.w};
      union { ushort s[16]; uint4 q[2]; } uh, ul;
#pragma unroll
      for (int j = 0; j < 16; ++j) {
        const float z = xpv * zz[j];
        const uint hb = bf16_rne_hibits(z);
        uh.s[j] = hb >> 16;
        const float r = z - __uint_as_float(hb);
        ul.s[j] = bf16_rne_hibits(r) >> 16;
      }
      const int zo = zn * 40 + zko;
      *(uint4*)&zhi[zo] = uh.q[0];
      *(uint4*)&zhi[zo + 8] = uh.q[1];
      *(uint4*)&zlo[zo] = ul.q[0];
      *(uint4*)&zlo[zo + 8] = ul.q[1];
    }

    __syncthreads();

    bf16x8 Ah[4], Al[4], Bh[4], Bl[4];
#pragma unroll
    for (int i = 0; i < 4; ++i) {
      Ah[i] = *(const bf16x8*)&zhi[aoff[i]];
      Al[i] = *(const bf16x8*)&zlo[aoff[i]];
    }
#pragma unroll
    for (int j = 0; j < 4; ++j) {
      Bh[j] = *(const bf16x8*)&whi[boff[j]];
      Bl[j] = *(const bf16x8*)&wlo[boff[j]];
    }
#pragma unroll
    for (int i = 0; i < 4; ++i)
#pragma unroll
      for (int j = 0; j < 4; ++j) {
        acc[i][j] = __builtin_amdgcn_mfma_f32_16x16x32_bf16(Ah[i], Bh[j], acc[i][j], 0, 0, 0);
        acc[i][j] = __builtin_amdgcn_mfma_f32_16x16x32_bf16(Ah[i], Bl[j], acc[i][j], 0, 0, 0);
        acc[i][j] = __builtin_amdgcn_mfma_f32_16x16x32_bf16(Al[i], Bh[j], acc[i][j], 0, 0, 0);
      }
  }

#pragma unroll
  for (int i = 0; i < 4; ++i)
#pragma unroll
    for (int j = 0; j < 4; ++j) {
      const int row = n0 + wr + i * 16 + (l >> 4) * 4;
      const int col = h0 + wc + j * 16 + (l & 15);
#pragma unroll
      for (int r = 0; r < 4; ++r)
        atomicAdd(&xout[(size_t)(row + r) * HD + col], acc[i][j][r]);
    }
}

// ---------------------------------------------------------------------------
// K2: xt[k][n][d] = sum_h (x[n][h]+b[h]) * Wt[k][d][h]
// ---------------------------------------------------------------------------
__global__ __launch_bounds__(256) void k2_xt(
    const float* __restrict__ x, const float* __restrict__ bb,
    const float* __restrict__ Wt, float* __restrict__ xt) {
  __shared__ float x_t[64][68];
  __shared__ float wt_t[64][68];
  const int t = threadIdx.x;
  const int n0 = blockIdx.x * 64;
  const int k = blockIdx.y;
  const int nb = 4 * (t & 15), db = 4 * (t >> 4);
  float acc[4][4] = {{0.f, 0.f, 0.f, 0.f}, {0.f, 0.f, 0.f, 0.f},
                     {0.f, 0.f, 0.f, 0.f}, {0.f, 0.f, 0.f, 0.f}};
  for (int h0 = 0; h0 < HD; h0 += 64) {
    __syncthreads();
    for (int idx = t; idx < 4096; idx += 256) {
      int hl = idx & 63, r = idx >> 6;
      x_t[hl][r] = x[(n0 + r) * HD + h0 + hl] + bb[h0 + hl];
      wt_t[hl][r] = Wt[k * (DD * HD) + r * HD + h0 + hl];
    }
    __syncthreads();
#pragma unroll 8
    for (int h = 0; h < 64; ++h) {
      const float4 xv = *(const float4*)&x_t[h][nb];
      const float4 wv = *(const float4*)&wt_t[h][db];
      acc[0][0] += xv.x * wv.x; acc[0][1] += xv.x * wv.y;
      acc[0][2] += xv.x * wv.z; acc[0][3] += xv.x * wv.w;
      acc[1][0] += xv.y * wv.x; acc[1][1] += xv.y * wv.y;
      acc[1][2] += xv.y * wv.z; acc[1][3] += xv.y * wv.w;
      acc[2][0] += xv.z * wv.x; acc[2][1] += xv.z * wv.y;
      acc[2][2] += xv.z * wv.z; acc[2][3] += xv.z * wv.w;
      acc[3][0] += xv.w * wv.x; acc[3][1] += xv.w * wv.y;
      acc[3][2] += xv.w * wv.z; acc[3][3] += xv.w * wv.w;
    }
  }
#pragma unroll
  for (int i = 0; i < 4; ++i) {
    float4 o;
    o.x = acc[i][0]; o.y = acc[i][1]; o.z = acc[i][2]; o.w = acc[i][3];
    *(float4*)&xt[(k * NN + n0 + nb + i) * DD + db] = o;
  }
}

// ---------------------------------------------------------------------------
// K3: u = xt·a_src, v = xt·a_dst
// ---------------------------------------------------------------------------
__global__ __launch_bounds__(256) void k3_scores(
    const float* __restrict__ xt, const float* __restrict__ av,
    float* __restrict__ ssrc, float* __restrict__ sdst) {
  const int tid = blockIdx.x * 256 + threadIdx.x;
  const int k = tid >> 12;
  const float* xr = xt + (long)tid * DD;
  const float* a = av + k * (2 * DD);
  float s1 = 0.f, s2 = 0.f;
#pragma unroll
  for (int d = 0; d < DD; d += 4) {
    const float4 xv = *(const float4*)&xr[d];
    const float4 a1 = *(const float4*)&a[d];
    const float4 a2 = *(const float4*)&a[DD + d];
    s1 += xv.x * a1.x + xv.y * a1.y + xv.z * a1.z + xv.w * a1.w;
    s2 += xv.x * a2.x + xv.y * a2.y + xv.z * a2.z + xv.w * a2.w;
  }
  ssrc[tid] = s1;
  sdst[tid] = s2;
}

// ---------------------------------------------------------------------------
// K4a: per-head bitonic sort of v (ascending) with permutation
// ---------------------------------------------------------------------------
__global__ __launch_bounds__(1024) void k4_sort(
    const float* __restrict__ sdst, float* __restrict__ vsorted,
    int* __restrict__ perm) {
  __shared__ float v[4096];
  __shared__ int ix[4096];
  const int k = blockIdx.x, t = threadIdx.x;
  for (int i = t; i < 4096; i += 1024) { v[i] = sdst[k * NN + i]; ix[i] = i; }
  __syncthreads();
  for (int len = 2; len <= 4096; len <<= 1) {
    for (int s = len >> 1; s > 0; s >>= 1) {
      for (int i = t; i < 4096; i += 1024) {
        const int j = i ^ s;
        if (j > i) {
          const bool asc = ((i & len) == 0);
          const float a = v[i], b = v[j];
          if ((a > b) == asc) {
            v[i] = b; v[j] = a;
            const int tmp = ix[i]; ix[i] = ix[j]; ix[j] = tmp;
          }
        }
      }
      __syncthreads();
    }
  }
  for (int i = t; i < 4096; i += 1024) {
    vsorted[k * NN + i] = v[i];
    perm[k * NN + i] = ix[i];
  }
}

// ---------------------------------------------------------------------------
// K4b: per-(head,chunk) sums of e^v·xt (hi) and e^{0.2v}·xt (lo); slot 64 = weight
// ---------------------------------------------------------------------------
__global__ __launch_bounds__(128) void k4b_chunksum(
    const float* __restrict__ vs, const int* __restrict__ perm,
    const float* __restrict__ xt, float* __restrict__ Chi, float* __restrict__ Clo) {
  const int c = blockIdx.x, k = blockIdx.y, t = threadIdx.x;
  if (t >= 65) return;
  const int base = k * NN + c * 64;
  float shi = 0.f, slo = 0.f;
  for (int i = 0; i < 64; ++i) {
    const float v = vs[base + i];
    const int p = perm[base + i];
    const float val = (t < 64) ? xt[((size_t)(k * NN + p)) * DD + t] : 1.0f;
    shi += __expf(v) * val;
    slo += __expf(0.2f * v) * val;
  }
  Chi[(k * 64 + c) * 65 + t] = shi;
  Clo[(k * 64 + c) * 65 + t] = slo;
}

// ---------------------------------------------------------------------------
// K4c: scan chunk sums: CloS = exclusive prefix (fwd), ChiS = inclusive suffix
// ---------------------------------------------------------------------------
__global__ __launch_bounds__(128) void k4c_scan(
    const float* __restrict__ Chi, const float* __restrict__ Clo,
    float* __restrict__ ChiS, float* __restrict__ CloS) {
  const int k = blockIdx.x, t = threadIdx.x;
  if (t >= 65) return;
  float run = 0.f;
  for (int c = 0; c < 64; ++c) {
    const float tmp = Clo[(k * 64 + c) * 65 + t];
    CloS[(k * 64 + c) * 65 + t] = run;
    run += tmp;
  }
  run = 0.f;
  for (int c = 63; c >= 0; --c) {
    run += Chi[(k * 64 + c) * 65 + t];
    ChiS[(k * 64 + c) * 65 + t] = run;
  }
}

// ---------------------------------------------------------------------------
// K4d: expand to per-position arrays.
// Plo[pos] = sum_{i<pos} e^{0.2 v_i} xt_i   (exclusive prefix)
// Phi[pos] = sum_{i>=pos} e^{v_i} xt_i      (inclusive suffix, no subtraction)
// ---------------------------------------------------------------------------
__global__ __launch_bounds__(128) void k4d_expand(
    const float* __restrict__ vs, const int* __restrict__ perm,
    const float* __restrict__ xt, const float* __restrict__ ChiS,
    const float* __restrict__ CloS, float* __restrict__ Phi,
    float* __restrict__ Plo) {
  const int c = blockIdx.x, k = blockIdx.y, t = threadIdx.x;
  if (t >= 65) return;
  const int base = k * NN + c * 64;
  float run = CloS[(k * 64 + c) * 65 + t];
  for (int i = 0; i < 64; ++i) {
    const int pos = c * 64 + i;
    const float v = vs[base + i];
    const int p = perm[base + i];
    const float val = (t < 64) ? xt[((size_t)(k * NN + p)) * DD + t] : 1.0f;
    Plo[((size_t)(k * 4097) + pos) * 65 + t] = run;
    run += __expf(0.2f * v) * val;
  }
  if (c == 63) Plo[((size_t)(k * 4097) + 4096) * 65 + t] = run;
  run = (c < 63) ? ChiS[(k * 64 + c + 1) * 65 + t] : 0.f;
  for (int i = 63; i >= 0; --i) {
    const int pos = c * 64 + i;
    const float v = vs[base + i];
    const int p = perm[base + i];
    const float val = (t < 64) ? xt[((size_t)(k * NN + p)) * DD + t] : 1.0f;
    run += __expf(v) * val;
    Phi[((size_t)(k * 4097) + pos) * 65 + t] = run;
  }
  if (c == 63) Phi[((size_t)(k * 4097) + 4096) * 65 + t] = 0.f;
}

// ---------------------------------------------------------------------------
// K6: per query: binary search threshold, combine, tanh, store.
// ---------------------------------------------------------------------------
__global__ __launch_bounds__(256) void k6_final(
    const float* __restrict__ ssrc, const float* __restrict__ vsorted,
    const float* __restrict__ Phi, const float* __restrict__ Plo,
    float* __restrict__ out) {
  const int t = threadIdx.x;
  const int qi = blockIdx.x * 4 + (t >> 6);  // = k*4096 + n
  const int d = t & 63;
  const int k = qi >> 12, n = qi & 4095;
  const float u = ssrc[qi];
  const float thr = -u;
  const float* vs = vsorted + k * NN;
  int lo = 0, hi = 4096;
  while (lo < hi) {
    const int mid = (lo + hi) >> 1;
    if (vs[mid] < thr) lo = mid + 1; else hi = mid;
  }
  const size_t rb = ((size_t)(k * 4097) + lo) * 65;
  const float eu = __expf(u), el = __expf(0.2f * u);
  const float num = eu * Phi[rb + d] + el * Plo[rb + d];
  const float den = eu * Phi[rb + 64] + el * Plo[rb + 64];
  out[(size_t)n * (KH * DD) + k * DD + d] = tanhf(num / den);
}

extern "C" void kernel_launch(void* const* d_in, const int* in_sizes, int n_in,
                              void* d_out, int out_size, void* d_ws, size_t ws_size,
                              hipStream_t stream) {
  const float* xp = (const float*)d_in[0];
  const float* xn = (const float*)d_in[1];
  const float* W = (const float*)d_in[2];
  const float* bb = (const float*)d_in[3];
  const float* Wt = (const float*)d_in[4];
  const float* av = (const float*)d_in[5];
  float* out = (float*)d_out;

  char* ws = (char*)d_ws;
  ushort* Whi  = (ushort*)(ws);                     // 8 MB
  ushort* Wlo  = (ushort*)(ws + 8388608);           // 8 MB
  float* x     = (float*)(ws + 16777216);           // 4 MB
  float* xt    = (float*)(ws + 20971520);           // 8 MB
  float* ssrc  = (float*)(ws + 29360128);           // 128 KB
  float* sdst  = (float*)(ws + 29491200);           // 128 KB
  float* vsort = (float*)(ws + 29622272);           // 128 KB
  int*   perm  = (int*)  (ws + 29753344);           // 128 KB
  float* Chi   = (float*)(ws + 29884416);           // 130 KB
  float* Clo   = (float*)(ws + 30017536);           // 130 KB
  float* ChiS  = (float*)(ws + 30150656);           // 130 KB
  float* CloS  = (float*)(ws + 30283776);           // 130 KB
  float* Phi   = (float*)(ws + 30416896);           // 8.33 MB
  float* Plo   = (float*)(ws + 38938656);           // 8.33 MB  (end ~45.3 MB)

  k0_split<<<(HD * PP * QQ) / 1024, 256, 0, stream>>>(W, Whi, Wlo);
  k_zero<<<(NN * HD) / 256, 256, 0, stream>>>(x);
  k1_bilinear<<<dim3(NN / 128, HD / 128, 8), 256, 0, stream>>>(xp, xn, Whi, Wlo, x);
  k2_xt<<<dim3(NN / 64, KH), 256, 0, stream>>>(x, bb, Wt, xt);
  k3_scores<<<(KH * NN) / 256, 256, 0, stream>>>(xt, av, ssrc, sdst);
  k4_sort<<<KH, 1024, 0, stream>>>(sdst, vsort, perm);
  k4b_chunksum<<<dim3(64, KH), 128, 0, stream>>>(vsort, perm, xt, Chi, Clo);
  k4c_scan<<<KH, 128, 0, stream>>>(Chi, Clo, ChiS, CloS);
  k4d_expand<<<dim3(64, KH), 128, 0, stream>>>(vsort, perm, xt, ChiS, CloS, Phi, Plo);
  k6_final<<<(KH * NN) / 4, 256, 0, stream>>>(ssrc, vsort, Phi, Plo, out);
}